// Round 16
// baseline (2363.350 us; speedup 1.0000x reference)
//
#include <hip/hip_runtime.h>

typedef unsigned short u16;
typedef __bf16 bf16x8 __attribute__((ext_vector_type(8)));
typedef float f32x4 __attribute__((ext_vector_type(4)));
typedef u16 u16x4 __attribute__((ext_vector_type(4)));
typedef u16 u16x8 __attribute__((ext_vector_type(8)));

__device__ __forceinline__ u16 f2bf(float f) {
  union { float f; unsigned u; } v; v.f = f;
  return (u16)((v.u + 0x7fffu + ((v.u >> 16) & 1u)) >> 16);
}
__device__ __forceinline__ float b2f(u16 h) {
  union { unsigned u; float f; } v; v.u = ((unsigned)h) << 16; return v.f;
}

__device__ __forceinline__ void gld16(const void* g, void* l) {
  __builtin_amdgcn_global_load_lds(
      (const __attribute__((address_space(1))) unsigned int*)g,
      (__attribute__((address_space(3))) unsigned int*)l, 16, 0, 0);
}

#define BAR() asm volatile("s_barrier" ::: "memory")
#define VMC6() asm volatile("s_waitcnt vmcnt(6)" ::: "memory")
#define VMC0() asm volatile("s_waitcnt vmcnt(0)" ::: "memory")

// ---- fused f32->bf16 tails (2359296 f32x4 = one 3072x3072 weight chunk) ----
__device__ __forceinline__ void cvt_tail_c(const float* __restrict__ src,
                                           u16* __restrict__ dst, int gtid, int gsz) {
  for (int i = gtid; i < 2359296; i += gsz) {
    f32x4 v = *(const f32x4*)(src + (size_t)i * 4);
    u16x4 b = { f2bf(v[0]), f2bf(v[1]), f2bf(v[2]), f2bf(v[3]) };
    *(u16x4*)(dst + (size_t)i * 4) = b;
  }
}
// strided: src row = 12288 f32 (3072 f32x4); chunk col offset k04 (f32x4 units)
__device__ __forceinline__ void cvt_tail_s(const float* __restrict__ src,
                                           u16* __restrict__ dst, int k04,
                                           int gtid, int gsz) {
  for (int i = gtid; i < 2359296; i += gsz) {
    int n = i / 768, cc = i - n * 768;
    f32x4 v = *(const f32x4*)(src + ((size_t)n * 3072 + k04 + cc) * 4);
    u16x4 b = { f2bf(v[0]), f2bf(v[1]), f2bf(v[2]), f2bf(v[3]) };
    *(u16x4*)(dst + (size_t)i * 4) = b;
  }
}

// ---------------- prep: xb = bf16(x + ee) ----------------
__global__ __launch_bounds__(256) void prep_kernel(const float* __restrict__ x,
                                                   const float* __restrict__ ee,
                                                   u16* __restrict__ xb) {
  size_t i = ((size_t)blockIdx.x * 256 + threadIdx.x) * 4;
  int col = (int)(i % 3072);
  f32x4 v = *(const f32x4*)&x[i];
  f32x4 e = *(const f32x4*)&ee[col];
  v += e;
  u16x4 b = { f2bf(v[0]), f2bf(v[1]), f2bf(v[2]), f2bf(v[3]) };
  *(u16x4*)&xb[i] = b;
}

// ---------------- f32 -> bf16 (contiguous) ----------------
__global__ __launch_bounds__(256) void cvt_kernel(const float* __restrict__ in,
                                                  u16* __restrict__ out, size_t n) {
  size_t i = ((size_t)blockIdx.x * 256 + threadIdx.x) * 4;
  if (i >= n) return;
  f32x4 v = *(const f32x4*)&in[i];
  u16x4 b = { f2bf(v[0]), f2bf(v[1]), f2bf(v[2]), f2bf(v[3]) };
  *(u16x4*)&out[i] = b;
}

// ======== unified 256x128 GEMM, triple-buffer, N-sliced XCD mapping ========
// N = 3072 for every call (ntile 24). One barrier per K64-tile, vmcnt(6) gate.
// EPI 0: bf16 = acc+bias           2: bf16 = gelu(acc+bias)
// EPI 3: bf16 = acc+bias+residf+ee 8: bf16 = acc+bias+b2f(residb)
// EPI 9: bf16 = b2f(oldC) + acc
// Optional fused cvt tails: (cs1,cd1) contiguous chunk; (cs2,cd2,ck04) w2-strided.
template<int EPI>
__global__ __launch_bounds__(512, 2) void gemmu_kernel(const u16* __restrict__ A,
                                                       const u16* __restrict__ B,
                                                       const float* __restrict__ bias,
                                                       const float* __restrict__ residf,
                                                       const u16* __restrict__ residb,
                                                       const float* __restrict__ ee,
                                                       void* __restrict__ C0,
                                                       int N, int K,
                                                       const float* __restrict__ cs1,
                                                       u16* __restrict__ cd1,
                                                       const float* __restrict__ cs2,
                                                       u16* __restrict__ cd2,
                                                       int ck04) {
  __shared__ __align__(16) u16 lds[73728];   // 3 bufs x (A 16384 | B 8192)
  const int tid = threadIdx.x;
  const int lane = tid & 63;
  const int w = tid >> 6;
  const int lr = lane & 15, lc8 = (lane >> 4) * 8;
  const int wm64 = (w >> 1) * 64;
  const int wn64 = (w & 1) * 64;
  const int rsw = (lr & 7) << 3;

  const int ntile = N >> 7;          // 24
  const int nper = ntile >> 3;       // 3
  const int bid = blockIdx.x;
  const int xcd = bid & 7;
  const int local = bid >> 3;
  const int bn = xcd * nper + local % nper;
  const int bm = local / nper;
  const size_t m0 = (size_t)bm << 8, n0 = (size_t)bn << 7;

  const int jsw = (tid & 7) ^ ((tid >> 3) & 7);
  const u16* gA = A + (m0 + (tid >> 3)) * (size_t)K + jsw * 8;
  const u16* gB = B + (n0 + (tid >> 3)) * (size_t)K + jsw * 8;
  u16* lA = &lds[tid * 8];
  u16* lB = &lds[16384 + tid * 8];

  f32x4 acc[4][4] = {};
  bf16x8 af[2][4], bfr[2][4];

  const int NT = K >> 6;   // 48; % 3 == 0

  auto stageA2 = [&](int buf, int kk) {
    gld16(gA + kk, lA + buf * 24576);
    gld16(gA + (size_t)64 * K + kk, lA + buf * 24576 + 64 * 64);
    gld16(gA + (size_t)128 * K + kk, lA + buf * 24576 + 128 * 64);
    gld16(gA + (size_t)192 * K + kk, lA + buf * 24576 + 192 * 64);
  };
  auto stageB2 = [&](int buf, int kk) {
    gld16(gB + kk, lB + buf * 24576);
    gld16(gB + (size_t)64 * K + kk, lB + buf * 24576 + 64 * 64);
  };
  auto LA = [&](int buf) {
#pragma unroll
    for (int ks = 0; ks < 2; ++ks)
#pragma unroll
      for (int f = 0; f < 4; ++f) {
        int r = wm64 + f * 16 + lr;
        af[ks][f] = *(const bf16x8*)&lds[buf * 24576 + r * 64 + ((ks * 32 + lc8) ^ rsw)];
      }
  };
  auto LBall = [&](int buf) {
#pragma unroll
    for (int ks = 0; ks < 2; ++ks)
#pragma unroll
      for (int f = 0; f < 4; ++f) {
        int r = wn64 + f * 16 + lr;
        bfr[ks][f] = *(const bf16x8*)&lds[buf * 24576 + 16384 + r * 64 + ((ks * 32 + lc8) ^ rsw)];
      }
  };
  auto MMA = [&]() {
    __builtin_amdgcn_s_setprio(1);
#pragma unroll
    for (int ks = 0; ks < 2; ++ks)
#pragma unroll
      for (int f = 0; f < 4; ++f)
#pragma unroll
        for (int f2 = 0; f2 < 4; ++f2)
          acc[f][f2] = __builtin_amdgcn_mfma_f32_16x16x32_bf16(
              af[ks][f], bfr[ks][f2], acc[f][f2], 0, 0, 0);
    __builtin_amdgcn_s_setprio(0);
  };
  auto TILE = [&](int bc, int bs, int tt) {
    const int kk2 = (tt + 2) << 6;
    const bool p = (tt + 2) < NT;
    LA(bc); LBall(bc);
    if (p) { stageA2(bs, kk2); stageB2(bs, kk2); }
    MMA();
    if (p) { VMC6(); } else { VMC0(); }
    BAR();
  };

  stageA2(0, 0); stageB2(0, 0);
  stageA2(1, 64); stageB2(1, 64);
  VMC6();
  BAR();

  for (int t = 0; t < NT; t += 3) {
    TILE(0, 2, t);
    TILE(1, 0, t + 1);
    TILE(2, 1, t + 2);
  }

  // -------- epilogue: acc -> swizzled LDS -> coalesced row stores --------
#pragma unroll
  for (int nf = 0; nf < 4; ++nf) {
    const int colL = wn64 + nf * 16 + lr;
    const size_t col = n0 + colL;
    float bv = 0.f;
    if constexpr (EPI != 9) bv = bias[col];
    const int ci = colL >> 3;
#pragma unroll
    for (int f = 0; f < 4; ++f) {
#pragma unroll
      for (int rg = 0; rg < 4; ++rg) {
        const int rowL = wm64 + f * 16 + (lc8 >> 1) + rg;
        const size_t idx = (m0 + rowL) * (size_t)N + col;
        float v = acc[f][nf][rg] + bv;
        if constexpr (EPI == 2)
          v = 0.5f * v * (1.0f + erff(v * 0.7071067811865476f));
        if constexpr (EPI == 3) v += residf[idx] + ee[col];
        if constexpr (EPI == 8) v += b2f(residb[idx]);
        if constexpr (EPI == 9) v += b2f(((const u16*)C0)[idx]);
        const int fz = (rowL >> 2) & 7;
        lds[rowL * 128 + (((ci ^ fz) << 3) | (colL & 7))] = f2bf(v);
      }
    }
  }
  __syncthreads();
  const int row = tid >> 1, half = tid & 1;
  const int fro = (row >> 2) & 7;
  u16* gout = (u16*)C0 + (m0 + row) * (size_t)N + n0 + half * 64;
#pragma unroll
  for (int i = 0; i < 8; ++i) {
    const int ci = half * 8 + i;
    *(uint4*)&gout[i * 8] = *(const uint4*)&lds[row * 128 + ((ci ^ fro) << 3)];
  }

  // -------- fused weight-cvt tails (hidden under later CU-rounds) --------
  const int gtid = bid * 512 + tid;
  const int gsz = (int)gridDim.x * 512;
  if (cd1) cvt_tail_c(cs1, cd1, gtid, gsz);
  if (cd2) cvt_tail_s(cs2, cd2, ck04, gtid, gsz);
}

// ------ decode helper: 1792 blocks -> (grp,g,r,off, qt/jb, hl, s) ------
__device__ __forceinline__ void decode_blk(int bid, int& grp, int& g, int& r, int& off,
                                           int& q16, int& hl, int& s) {
  if (bid < 1024)      { grp = 0; g = 1024; r = 1; off = 0; }
  else if (bid < 1536) { grp = 1; g = 2048; r = 2; off = 1; bid -= 1024; }
  else                 { grp = 2; g = 4096; r = 4; off = 2; bid -= 1536; }
  q16 = bid & 15; hl = (bid >> 4) & 7; s = bid >> 7;
}

// ---------------- V transpose into dilated [.. d][j] layout ----------------
__global__ __launch_bounds__(256) void vtrans_kernel(const u16* __restrict__ Vb,
                                                     u16* __restrict__ vtd) {
  int grp, g, r, off, jb, hl, s;
  decode_blk(blockIdx.x, grp, g, r, off, jb, hl, s);
  const int h = grp * 8 + hl;
  const size_t vbase = (size_t)((grp == 0) ? 0u : (grp == 1) ? 8388608u : 12582912u)
                       + (size_t)(s * 8 + hl) * 131072;
  __shared__ u16 t[64 * 128];
  const int tid = threadIdx.x;
#pragma unroll
  for (int i = 0; i < 4; ++i) {
    int c = tid + i * 256;
    int jj = c >> 4, c16 = c & 15;
    size_t pos = (size_t)s * g + off + (size_t)(jb * 64 + jj) * r;
    uint4 d = *(const uint4*)&Vb[pos * 3072 + h * 128 + c16 * 8];
    *(uint4*)((char*)t + jj * 256 + ((c16 * 16) ^ ((jj >> 3) << 4))) = d;
  }
  __syncthreads();
#pragma unroll
  for (int i = 0; i < 4; ++i) {
    int c = tid + i * 256;
    int dd = c >> 3, jc = c & 7;
    u16x8 vals;
#pragma unroll
    for (int q = 0; q < 8; ++q) {
      int row = jc * 8 + q;
      vals[q] = *(const u16*)((const char*)t + row * 256 + ((dd * 2) ^ (jc << 4)));
    }
    *(u16x8*)&vtd[vbase + (size_t)dd * 1024 + jb * 64 + jc * 8] = vals;
  }
}

// ---------------- dilated flash attention (+ fused wout cvt tail) ----------------
__global__ __launch_bounds__(256) void attn_kernel(const u16* __restrict__ Qb,
                                                   const u16* __restrict__ Kb,
                                                   const u16* __restrict__ vtd,
                                                   u16* __restrict__ abuf,
                                                   const float* __restrict__ csrc,
                                                   u16* __restrict__ cdst) {
  int grp, g, r, off, qt, hl, s;
  decode_blk(blockIdx.x, grp, g, r, off, qt, hl, s);
  const int h = grp * 8 + hl;
  const size_t vbase = (size_t)((grp == 0) ? 0u : (grp == 1) ? 8388608u : 12582912u)
                       + (size_t)(s * 8 + hl) * 131072;
  const size_t segoff = (size_t)s * g + off;

  const int tid = threadIdx.x;
  const int lane = tid & 63, w = tid >> 6;
  const int lr = lane & 15, lc = lane >> 4;

  __shared__ u16 Kl[64 * 128];
  __shared__ u16 Vl[128 * 64];
  __shared__ u16 Pl[4][1024];

  const size_t qpos = segoff + (size_t)(qt * 64 + w * 16 + lr) * r;
  const u16* qrow = &Qb[qpos * 3072 + h * 128];
  bf16x8 qf[4];
#pragma unroll
  for (int kc = 0; kc < 4; ++kc) qf[kc] = *(const bf16x8*)&qrow[kc * 32 + lc * 8];

  float m_run[4], l_run[4];
  f32x4 ao[8] = {};
#pragma unroll
  for (int i = 0; i < 4; ++i) { m_run[i] = -1e30f; l_run[i] = 0.f; }

  const float scale = 0.08838834764831845f;

  for (int kt = 0; kt < 16; ++kt) {
    __syncthreads();
#pragma unroll
    for (int i = 0; i < 4; ++i) {
      int c = tid + i * 256;
      int jj = c >> 4, c16 = c & 15;
      size_t kpos = segoff + (size_t)(kt * 64 + jj) * r;
      uint4 kd = *(const uint4*)&Kb[kpos * 3072 + h * 128 + c16 * 8];
      *(uint4*)((char*)Kl + jj * 256 + ((c16 * 16) ^ ((jj & 7) << 4))) = kd;
      int dd = c >> 3, jc = c & 7;
      uint4 vd = *(const uint4*)&vtd[vbase + (size_t)dd * 1024 + kt * 64 + jc * 8];
      *(uint4*)((char*)Vl + dd * 128 + ((jc * 16) ^ ((dd & 7) << 4))) = vd;
    }
    __syncthreads();

    f32x4 sc4[4] = {};
#pragma unroll
    for (int kb = 0; kb < 4; ++kb) {
      const int key = kb * 16 + lr;
      const int swz = (key & 7) << 4;
#pragma unroll
      for (int kc = 0; kc < 4; ++kc) {
        bf16x8 kf = *(const bf16x8*)((const char*)Kl + key * 256 + ((kc * 64 + lc * 16) ^ swz));
        sc4[kb] = __builtin_amdgcn_mfma_f32_16x16x32_bf16(qf[kc], kf, sc4[kb], 0, 0, 0);
      }
    }

    float pv[4][4];
#pragma unroll
    for (int rg = 0; rg < 4; ++rg) {
      float t = fmaxf(fmaxf(sc4[0][rg], sc4[1][rg]), fmaxf(sc4[2][rg], sc4[3][rg]));
#pragma unroll
      for (int sh = 1; sh < 16; sh <<= 1) t = fmaxf(t, __shfl_xor(t, sh, 64));
      t *= scale;
      const float mn = fmaxf(m_run[rg], t);
      const float corr = __expf(m_run[rg] - mn);
      m_run[rg] = mn;
      float sum = 0.f;
#pragma unroll
      for (int kb = 0; kb < 4; ++kb) {
        float p = __expf(sc4[kb][rg] * scale - mn);
        pv[kb][rg] = p; sum += p;
      }
#pragma unroll
      for (int sh = 1; sh < 16; sh <<= 1) sum += __shfl_xor(sum, sh, 64);
      l_run[rg] = l_run[rg] * corr + sum;
#pragma unroll
      for (int nb = 0; nb < 8; ++nb) ao[nb][rg] *= corr;
    }

#pragma unroll
    for (int rg = 0; rg < 4; ++rg) {
      const int q = lc * 4 + rg;
      const int swq = (q & 7) << 4;
#pragma unroll
      for (int kb = 0; kb < 4; ++kb) {
        const int key = kb * 16 + lr;
        *(u16*)((char*)&Pl[w][0] + q * 128 + ((key * 2) ^ swq)) = f2bf(pv[kb][rg]);
      }
    }
    __syncthreads();

#pragma unroll
    for (int kc2 = 0; kc2 < 2; ++kc2) {
      bf16x8 pf = *(const bf16x8*)((const char*)&Pl[w][0] + lr * 128 + ((kc2 * 64 + lc * 16) ^ ((lr & 7) << 4)));
#pragma unroll
      for (int nb = 0; nb < 8; ++nb) {
        const int dd = nb * 16 + lr;
        bf16x8 vf = *(const bf16x8*)((const char*)Vl + dd * 128 + ((kc2 * 64 + lc * 16) ^ ((dd & 7) << 4)));
        ao[nb] = __builtin_amdgcn_mfma_f32_16x16x32_bf16(pf, vf, ao[nb], 0, 0, 0);
      }
    }
  }

#pragma unroll
  for (int rg = 0; rg < 4; ++rg) {
    const float inv = 1.f / l_run[rg];
    const size_t opos = segoff + (size_t)(qt * 64 + w * 16 + lc * 4 + rg) * r;
    u16* orow = &abuf[opos * 3072 + h * 128];
#pragma unroll
    for (int nb = 0; nb < 8; ++nb) orow[nb * 16 + lr] = f2bf(ao[nb][rg] * inv);
  }

  if (cdst) cvt_tail_c(csrc, cdst, blockIdx.x * 256 + tid, 1792 * 256);
}

// ---------------- LayerNorm over 3072 cols; IN_BF/OUT_BF select dtypes ----------------
template<int IN_BF, int OUT_BF>
__global__ __launch_bounds__(256) void ln_kernel(const void* __restrict__ yv,
                                                 const float* __restrict__ gm,
                                                 const float* __restrict__ bt,
                                                 void* __restrict__ outv) {
  const size_t row = blockIdx.x;
  const int tid = threadIdx.x;
  float v[12];
  float s = 0.f, ss = 0.f;
#pragma unroll
  for (int i = 0; i < 3; ++i) {
    if constexpr (IN_BF) {
      u16x4 raw = *(const u16x4*)((const u16*)yv + row * 3072 + tid * 4 + i * 1024);
#pragma unroll
      for (int j = 0; j < 4; ++j) { float f = b2f(raw[j]); v[i * 4 + j] = f; s += f; ss += f * f; }
    } else {
      f32x4 raw = *(const f32x4*)((const float*)yv + row * 3072 + tid * 4 + i * 1024);
#pragma unroll
      for (int j = 0; j < 4; ++j) { float f = raw[j]; v[i * 4 + j] = f; s += f; ss += f * f; }
    }
  }
#pragma unroll
  for (int sh = 1; sh < 64; sh <<= 1) { s += __shfl_xor(s, sh, 64); ss += __shfl_xor(ss, sh, 64); }
  __shared__ float red[8];
  if ((tid & 63) == 0) { red[tid >> 6] = s; red[4 + (tid >> 6)] = ss; }
  __syncthreads();
  s = red[0] + red[1] + red[2] + red[3];
  ss = red[4] + red[5] + red[6] + red[7];
  const float mean = s * (1.f / 3072.f);
  const float var = ss * (1.f / 3072.f) - mean * mean;
  const float rs = rsqrtf(var + 1e-5f);
#pragma unroll
  for (int i = 0; i < 3; ++i) {
    int c = tid * 4 + i * 1024;
    f32x4 g4 = *(const f32x4*)&gm[c];
    f32x4 b4 = *(const f32x4*)&bt[c];
    if constexpr (OUT_BF) {
      u16x4 ob;
#pragma unroll
      for (int j = 0; j < 4; ++j) ob[j] = f2bf((v[i * 4 + j] - mean) * rs * g4[j] + b4[j]);
      *(u16x4*)((u16*)outv + row * 3072 + c) = ob;
    } else {
      f32x4 o;
#pragma unroll
      for (int j = 0; j < 4; ++j) o[j] = (v[i * 4 + j] - mean) * rs * g4[j] + b4[j];
      *(f32x4*)((float*)outv + row * 3072 + c) = o;
    }
  }
}

// ---------------- launch ----------------
extern "C" void kernel_launch(void* const* d_in, const int* in_sizes, int n_in,
                              void* d_out, int out_size, void* d_ws, size_t ws_size,
                              hipStream_t stream) {
  (void)in_sizes; (void)n_in; (void)out_size;
  const float* x    = (const float*)d_in[0];
  const float* ee   = (const float*)d_in[1];
  const float* wqkv = (const float*)d_in[2];
  const float* bqkv = (const float*)d_in[3];
  const float* wout = (const float*)d_in[4];
  const float* bout = (const float*)d_in[5];
  const float* ln1g = (const float*)d_in[6];
  const float* ln1b = (const float*)d_in[7];
  const float* w1   = (const float*)d_in[8];
  const float* b1   = (const float*)d_in[9];
  const float* w2   = (const float*)d_in[10];
  const float* b2   = (const float*)d_in[11];
  const float* ln2g = (const float*)d_in[12];
  const float* ln2b = (const float*)d_in[13];
  float* out = (float*)d_out;

  static const size_t OFF_B1  = 50331648;
  static const size_t OFF_B2  = 100663296;
  static const size_t WS_NEED = 150994944;
  if (ws_size < WS_NEED) return;

  char* ws = (char*)d_ws;
  u16*   xb    = (u16*)(ws);           // B0: xb / vtd / x1b
  u16*   vtd   = (u16*)(ws);
  u16*   x1b   = (u16*)(ws);
  u16*   Qb    = (u16*)(ws + OFF_B1);  // B1: Qb / y1b / y2b
  u16*   y1b   = (u16*)(ws + OFF_B1);
  u16*   y2b   = (u16*)(ws + OFF_B1);
  u16*   wslot = (u16*)(ws + OFF_B2);  // B2: wslot / abuf / hc
  u16*   abuf  = (u16*)(ws + OFF_B2);
  u16*   hc    = (u16*)(ws + OFF_B2);

  // d_out arena (100.66 MB):
  u16* Kb    = (u16*)d_out;                     // [0, 50.33 MB) during attn
  u16* Vb    = (u16*)d_out + 25165824;          // [50.33, 100.66) until vtrans
  u16* woutb = (u16*)d_out + 25165824;          // wout bf16 (attn tail -> oproj)
  u16* sW1[2] = { (u16*)d_out + 0,        (u16*)d_out + 18874368 };
  u16* sW2[2] = { (u16*)d_out + 9437184,  (u16*)d_out + 28311552 };

  prep_kernel<<<24576, 256, 0, stream>>>(x, ee, xb);

  // Q,K: one cvt of both weight sections, two N=3072 GEMMs
  cvt_kernel<<<18432, 256, 0, stream>>>(wqkv, wslot, 18874368);
  gemmu_kernel<0><<<768, 512, 0, stream>>>(xb, wslot, bqkv, nullptr, nullptr, nullptr,
                                           Qb, 3072, 3072,
                                           nullptr, nullptr, nullptr, nullptr, 0);
  gemmu_kernel<0><<<768, 512, 0, stream>>>(xb, wslot + 9437184, bqkv + 3072, nullptr, nullptr, nullptr,
                                           Kb, 3072, 3072,
                                           nullptr, nullptr, nullptr, nullptr, 0);
  cvt_kernel<<<9216, 256, 0, stream>>>(wqkv + 18874368, wslot, 9437184);
  gemmu_kernel<0><<<768, 512, 0, stream>>>(xb, wslot, bqkv + 6144, nullptr, nullptr, nullptr,
                                           Vb, 3072, 3072,
                                           nullptr, nullptr, nullptr, nullptr, 0);

  vtrans_kernel<<<1792, 256, 0, stream>>>(Vb, vtd);
  hipMemsetAsync(abuf, 0, 50331648, stream);
  // attn + fused wout cvt (Vb region dead after vtrans)
  attn_kernel<<<1792, 256, 0, stream>>>(Qb, Kb, vtd, abuf, wout, woutb);

  // oproj + fused cvt of w1c0, w2c0 into d_out P0 (Kb dead after attn)
  gemmu_kernel<3><<<768, 512, 0, stream>>>(abuf, woutb, bout, x, nullptr, ee,
                                           y1b, 3072, 3072,
                                           w1, sW1[0], w2, sW2[0], 0);
  ln_kernel<1, 1><<<8192, 256, 0, stream>>>(y1b, ln1g, ln1b, x1b);

  // FFN: 4 chunks of 3072; slot ping-pong in d_out; y2 accumulates bf16 in y2b
  for (int c = 0; c < 4; ++c) {
    const int p = c & 1;
    const bool more = (c < 3);
    // FFN1-c: h = gelu(x1 @ w1c^T + b1c); fused cvt of w1(c+1) -> other slot
    gemmu_kernel<2><<<768, 512, 0, stream>>>(x1b, sW1[p], b1 + c * 3072, nullptr, nullptr, nullptr,
                                             hc, 3072, 3072,
                                             more ? (w1 + (size_t)(c + 1) * 9437184) : nullptr,
                                             more ? sW1[1 - p] : nullptr,
                                             nullptr, nullptr, 0);
    // FFN2-c: y2 (+)= h @ w2c^T (+ b2 + x1 at c0); fused cvt of w2(c+1)
    if (c == 0)
      gemmu_kernel<8><<<768, 512, 0, stream>>>(hc, sW2[0], b2, nullptr, x1b, nullptr,
                                               y2b, 3072, 3072,
                                               nullptr, nullptr,
                                               w2, sW2[1], 768);
    else
      gemmu_kernel<9><<<768, 512, 0, stream>>>(hc, sW2[p], b2, nullptr, nullptr, nullptr,
                                               y2b, 3072, 3072,
                                               nullptr, nullptr,
                                               more ? w2 : nullptr,
                                               more ? sW2[1 - p] : nullptr,
                                               (c + 1) * 768);
  }

  ln_kernel<1, 0><<<8192, 256, 0, stream>>>(y2b, ln2g, ln2b, out);
}

// Round 17
// 2155.468 us; speedup vs baseline: 1.0964x; 1.0964x over previous
//
#include <hip/hip_runtime.h>

typedef unsigned short u16;
typedef __bf16 bf16x8 __attribute__((ext_vector_type(8)));
typedef float f32x4 __attribute__((ext_vector_type(4)));
typedef u16 u16x4 __attribute__((ext_vector_type(4)));
typedef u16 u16x8 __attribute__((ext_vector_type(8)));

__device__ __forceinline__ u16 f2bf(float f) {
  union { float f; unsigned u; } v; v.f = f;
  return (u16)((v.u + 0x7fffu + ((v.u >> 16) & 1u)) >> 16);
}
__device__ __forceinline__ float b2f(u16 h) {
  union { unsigned u; float f; } v; v.u = ((unsigned)h) << 16; return v.f;
}

__device__ __forceinline__ void gld16(const void* g, void* l) {
  __builtin_amdgcn_global_load_lds(
      (const __attribute__((address_space(1))) unsigned int*)g,
      (__attribute__((address_space(3))) unsigned int*)l, 16, 0, 0);
}

#define BAR() asm volatile("s_barrier" ::: "memory")
#define VMC4() asm volatile("s_waitcnt vmcnt(4)" ::: "memory")
#define VMC6() asm volatile("s_waitcnt vmcnt(6)" ::: "memory")
#define VMC0() asm volatile("s_waitcnt vmcnt(0)" ::: "memory")

// ---------------- prep: xb = bf16(x + ee) ----------------
__global__ __launch_bounds__(256) void prep_kernel(const float* __restrict__ x,
                                                   const float* __restrict__ ee,
                                                   u16* __restrict__ xb) {
  size_t i = ((size_t)blockIdx.x * 256 + threadIdx.x) * 4;
  int col = (int)(i % 3072);
  f32x4 v = *(const f32x4*)&x[i];
  f32x4 e = *(const f32x4*)&ee[col];
  v += e;
  u16x4 b = { f2bf(v[0]), f2bf(v[1]), f2bf(v[2]), f2bf(v[3]) };
  *(u16x4*)&xb[i] = b;
}

// ---------------- f32 -> bf16 (contiguous) ----------------
__global__ __launch_bounds__(256) void cvt_kernel(const float* __restrict__ in,
                                                  u16* __restrict__ out, size_t n) {
  size_t i = ((size_t)blockIdx.x * 256 + threadIdx.x) * 4;
  if (i >= n) return;
  f32x4 v = *(const f32x4*)&in[i];
  u16x4 b = { f2bf(v[0]), f2bf(v[1]), f2bf(v[2]), f2bf(v[3]) };
  *(u16x4*)&out[i] = b;
}

// ---- strided cvt: out[3072][6144] = bf16(w2[n][k0+k]), w2 row stride 12288 ----
__global__ __launch_bounds__(256) void cvt_strided_kernel(const float* __restrict__ in,
                                                          u16* __restrict__ out, int k0) {
  size_t i = ((size_t)blockIdx.x * 256 + threadIdx.x) * 4;
  int n = (int)(i / 6144), k = (int)(i % 6144);
  f32x4 v = *(const f32x4*)&in[(size_t)n * 12288 + k0 + k];
  u16x4 b = { f2bf(v[0]), f2bf(v[1]), f2bf(v[2]), f2bf(v[3]) };
  *(u16x4*)&out[i] = b;
}

// ======== 256x256 8-phase GEMM, B-resident, N-sliced XCD mapping ========
// EPI 2: bf16 = gelu(acc+bias)   7: 2-section split bf16 (QK), ldc=3072
template<int EPI>
__global__ __launch_bounds__(512, 2) void gemm8_kernel(const u16* __restrict__ A,
                                                       const u16* __restrict__ B,
                                                       const float* __restrict__ bias,
                                                       void* __restrict__ C0,
                                                       void* __restrict__ C1,
                                                       int N, int K) {
  __shared__ __align__(16) u16 lds[65536];   // [buf][A:16384|B:16384] u16
  const int tid = threadIdx.x;
  const int lane = tid & 63;
  const int w = tid >> 6;
  const int lr = lane & 15, lc8 = (lane >> 4) * 8;
  const int wm128 = (w >> 2) * 128, wn64 = (w & 3) * 64;
  const int rsw = (lr & 7) << 3;

  // N-sliced XCD mapping: each XCD owns ntile/8 consecutive bn across all bm.
  const int ntile = N >> 8;          // 24 for our shapes
  const int nper = ntile >> 3;       // 3
  const int bid = blockIdx.x;
  const int xcd = bid & 7;
  const int local = bid >> 3;
  const int bn = xcd * nper + local % nper;
  const int bm = local / nper;
  const size_t m0 = (size_t)bm << 8, n0 = (size_t)bn << 8;

  const int jsw = (tid & 7) ^ ((tid >> 3) & 7);
  const u16* gA = A + (m0 + (tid >> 3)) * (size_t)K + jsw * 8;
  const u16* gB = B + (n0 + ((tid >> 8) << 6) + ((tid >> 3) & 31)) * (size_t)K + jsw * 8;
  u16* lA = &lds[tid * 8];
  u16* lB = &lds[16384 + (((tid >> 8) << 12) | (((tid >> 3) & 31) << 6) | ((tid & 7) << 3))];

  f32x4 acc[8][4] = {};
  bf16x8 af[2][2], bfr[2][4];

  auto stageA = [&](int buf, int mh, int kk) {
    const int ro = mh * 64;
    gld16(gA + (size_t)ro * K + kk, lA + buf * 32768 + ro * 64);
    gld16(gA + (size_t)(ro + 128) * K + kk, lA + buf * 32768 + (ro + 128) * 64);
  };
  auto stageB = [&](int buf, int nh, int kk) {
    const int ro = nh * 32;
    gld16(gB + (size_t)ro * K + kk, lB + buf * 32768 + ro * 64);
    gld16(gB + (size_t)(ro + 128) * K + kk, lB + buf * 32768 + (ro + 128) * 64);
  };
  auto LA2 = [&](int buf, int p) {
#pragma unroll
    for (int ks = 0; ks < 2; ++ks)
#pragma unroll
      for (int j = 0; j < 2; ++j) {
        int r = wm128 + (2 * p + j) * 16 + lr;
        af[ks][j] = *(const bf16x8*)&lds[buf * 32768 + r * 64 + ((ks * 32 + lc8) ^ rsw)];
      }
  };
  auto LBall = [&](int buf) {
#pragma unroll
    for (int ks = 0; ks < 2; ++ks)
#pragma unroll
      for (int f2 = 0; f2 < 4; ++f2) {
        int r = wn64 + f2 * 16 + lr;
        bfr[ks][f2] = *(const bf16x8*)&lds[buf * 32768 + 16384 + r * 64 + ((ks * 32 + lc8) ^ rsw)];
      }
  };
  auto MMA = [&](int p) {
    __builtin_amdgcn_s_setprio(1);
#pragma unroll
    for (int ks = 0; ks < 2; ++ks)
#pragma unroll
      for (int j = 0; j < 2; ++j)
#pragma unroll
        for (int f2 = 0; f2 < 4; ++f2)
          acc[2 * p + j][f2] = __builtin_amdgcn_mfma_f32_16x16x32_bf16(
              af[ks][j], bfr[ks][f2], acc[2 * p + j][f2], 0, 0, 0);
    __builtin_amdgcn_s_setprio(0);
  };

  // prologue: tile0 full -> buf0; tile1 A_mh0,B_nh1 -> buf1; vmcnt(4) completes t0
  stageA(0, 0, 0); stageB(0, 1, 0); stageA(0, 1, 0); stageB(0, 0, 0);
  stageA(1, 0, 64); stageB(1, 1, 64);
  VMC4();
  BAR();

  const int NIT = K >> 7;   // K % 128 == 0
  for (int it = 0; it < NIT; ++it) {
    const int kk = it << 7;
    const bool pred = (it + 1 < NIT);
    LBall(0); LA2(0, 0);
    stageA(1, 1, kk + 64);
    BAR(); MMA(0); BAR();
    LA2(0, 1);
    stageB(1, 0, kk + 64);
    BAR(); MMA(1); BAR();
    LA2(0, 2);
    if (pred) stageA(0, 0, kk + 128);
    BAR(); MMA(2); BAR();
    LA2(0, 3);
    if (pred) stageB(0, 1, kk + 128);
    BAR(); MMA(3);
    if (pred) { VMC4(); } else { VMC0(); }
    BAR();
    LBall(1); LA2(1, 0);
    if (pred) stageA(0, 1, kk + 128);
    BAR(); MMA(0); BAR();
    LA2(1, 1);
    if (pred) stageB(0, 0, kk + 128);
    BAR(); MMA(1); BAR();
    LA2(1, 2);
    if (pred) stageA(1, 0, kk + 192);
    BAR(); MMA(2); BAR();
    LA2(1, 3);
    if (pred) stageB(1, 1, kk + 192);
    BAR(); MMA(3);
    if (pred) { VMC4(); }
    BAR();
  }

  // -------- epilogue: direct scalar stores --------
#pragma unroll
  for (int ni = 0; ni < 4; ++ni) {
    const size_t col = n0 + wn64 + ni * 16 + lr;
    const float bv = bias[col];
    u16* dstb;
    size_t colw = col;
    int ldc;
    if constexpr (EPI == 7) {
      const int sec = (int)(col / 3072);
      dstb = sec ? (u16*)C1 : (u16*)C0;
      colw = col - (size_t)sec * 3072;
      ldc = 3072;
    } else {
      dstb = (u16*)C0; ldc = N;
    }
#pragma unroll
    for (int mi = 0; mi < 8; ++mi) {
#pragma unroll
      for (int rg = 0; rg < 4; ++rg) {
        const size_t row = m0 + wm128 + mi * 16 + (lc8 >> 1) + rg;
        float v = acc[mi][ni][rg] + bv;
        if constexpr (EPI == 2)
          v = 0.5f * v * (1.0f + erff(v * 0.7071067811865476f));
        dstb[row * ldc + colw] = f2bf(v);
      }
    }
  }
}

// ======== unified 256x128 GEMM, triple-buffer, N-sliced XCD mapping ========
// EPI 0: bf16 = acc+bias           3: bf16 = acc+bias+residf+ee
// EPI 8: bf16 = acc+bias+b2f(residb)   9: bf16 = b2f(oldC) + acc
template<int EPI>
__global__ __launch_bounds__(512, 2) void gemmu_kernel(const u16* __restrict__ A,
                                                       const u16* __restrict__ B,
                                                       const float* __restrict__ bias,
                                                       const float* __restrict__ residf,
                                                       const u16* __restrict__ residb,
                                                       const float* __restrict__ ee,
                                                       void* __restrict__ C0,
                                                       int N, int K) {
  __shared__ __align__(16) u16 lds[73728];   // 3 bufs x (A 16384 | B 8192)
  const int tid = threadIdx.x;
  const int lane = tid & 63;
  const int w = tid >> 6;
  const int lr = lane & 15, lc8 = (lane >> 4) * 8;
  const int wm64 = (w >> 1) * 64;
  const int wn64 = (w & 1) * 64;
  const int rsw = (lr & 7) << 3;

  const int ntile = N >> 7;          // 24
  const int nper = ntile >> 3;       // 3
  const int bid = blockIdx.x;
  const int xcd = bid & 7;
  const int local = bid >> 3;
  const int bn = xcd * nper + local % nper;
  const int bm = local / nper;
  const size_t m0 = (size_t)bm << 8, n0 = (size_t)bn << 7;

  const int jsw = (tid & 7) ^ ((tid >> 3) & 7);
  const u16* gA = A + (m0 + (tid >> 3)) * (size_t)K + jsw * 8;
  const u16* gB = B + (n0 + (tid >> 3)) * (size_t)K + jsw * 8;
  u16* lA = &lds[tid * 8];
  u16* lB = &lds[16384 + tid * 8];

  f32x4 acc[4][4] = {};
  bf16x8 af[2][4], bfr[2][4];

  const int NT = K >> 6;   // NT % 3 == 0 (48 or 96)

  auto stageA2 = [&](int buf, int kk) {
    gld16(gA + kk, lA + buf * 24576);
    gld16(gA + (size_t)64 * K + kk, lA + buf * 24576 + 64 * 64);
    gld16(gA + (size_t)128 * K + kk, lA + buf * 24576 + 128 * 64);
    gld16(gA + (size_t)192 * K + kk, lA + buf * 24576 + 192 * 64);
  };
  auto stageB2 = [&](int buf, int kk) {
    gld16(gB + kk, lB + buf * 24576);
    gld16(gB + (size_t)64 * K + kk, lB + buf * 24576 + 64 * 64);
  };
  auto LA = [&](int buf) {
#pragma unroll
    for (int ks = 0; ks < 2; ++ks)
#pragma unroll
      for (int f = 0; f < 4; ++f) {
        int r = wm64 + f * 16 + lr;
        af[ks][f] = *(const bf16x8*)&lds[buf * 24576 + r * 64 + ((ks * 32 + lc8) ^ rsw)];
      }
  };
  auto LBall = [&](int buf) {
#pragma unroll
    for (int ks = 0; ks < 2; ++ks)
#pragma unroll
      for (int f = 0; f < 4; ++f) {
        int r = wn64 + f * 16 + lr;
        bfr[ks][f] = *(const bf16x8*)&lds[buf * 24576 + 16384 + r * 64 + ((ks * 32 + lc8) ^ rsw)];
      }
  };
  auto MMA = [&]() {
    __builtin_amdgcn_s_setprio(1);
#pragma unroll
    for (int ks = 0; ks < 2; ++ks)
#pragma unroll
      for (int f = 0; f < 4; ++f)
#pragma unroll
        for (int f2 = 0; f2 < 4; ++f2)
          acc[f][f2] = __builtin_amdgcn_mfma_f32_16x16x32_bf16(
              af[ks][f], bfr[ks][f2], acc[f][f2], 0, 0, 0);
    __builtin_amdgcn_s_setprio(0);
  };
  auto TILE = [&](int bc, int bs, int tt) {
    const int kk2 = (tt + 2) << 6;
    const bool p = (tt + 2) < NT;
    LA(bc); LBall(bc);
    if (p) { stageA2(bs, kk2); stageB2(bs, kk2); }
    MMA();
    if (p) { VMC6(); } else { VMC0(); }
    BAR();
  };

  stageA2(0, 0); stageB2(0, 0);
  stageA2(1, 64); stageB2(1, 64);
  VMC6();
  BAR();

  for (int t = 0; t < NT; t += 3) {
    TILE(0, 2, t);
    TILE(1, 0, t + 1);
    TILE(2, 1, t + 2);
  }

  // -------- epilogue: acc -> swizzled LDS -> coalesced row stores --------
#pragma unroll
  for (int nf = 0; nf < 4; ++nf) {
    const int colL = wn64 + nf * 16 + lr;
    const size_t col = n0 + colL;
    float bv = 0.f;
    if constexpr (EPI != 9) bv = bias[col];
    const int ci = colL >> 3;
#pragma unroll
    for (int f = 0; f < 4; ++f) {
#pragma unroll
      for (int rg = 0; rg < 4; ++rg) {
        const int rowL = wm64 + f * 16 + (lc8 >> 1) + rg;
        const size_t idx = (m0 + rowL) * (size_t)N + col;
        float v = acc[f][nf][rg] + bv;
        if constexpr (EPI == 3) v += residf[idx] + ee[col];
        if constexpr (EPI == 8) v += b2f(residb[idx]);
        if constexpr (EPI == 9) v += b2f(((const u16*)C0)[idx]);
        const int fz = (rowL >> 2) & 7;
        lds[rowL * 128 + (((ci ^ fz) << 3) | (colL & 7))] = f2bf(v);
      }
    }
  }
  __syncthreads();
  const int row = tid >> 1, half = tid & 1;
  const int fro = (row >> 2) & 7;
  u16* gout = (u16*)C0 + (m0 + row) * (size_t)N + n0 + half * 64;
#pragma unroll
  for (int i = 0; i < 8; ++i) {
    const int ci = half * 8 + i;
    *(uint4*)&gout[i * 8] = *(const uint4*)&lds[row * 128 + ((ci ^ fro) << 3)];
  }
}

// ------ decode helper: 1792 blocks -> (grp,g,r,off, qt/jb, hl, s) ------
__device__ __forceinline__ void decode_blk(int bid, int& grp, int& g, int& r, int& off,
                                           int& q16, int& hl, int& s) {
  if (bid < 1024)      { grp = 0; g = 1024; r = 1; off = 0; }
  else if (bid < 1536) { grp = 1; g = 2048; r = 2; off = 1; bid -= 1024; }
  else                 { grp = 2; g = 4096; r = 4; off = 2; bid -= 1536; }
  q16 = bid & 15; hl = (bid >> 4) & 7; s = bid >> 7;
}

// ---------------- V transpose into dilated [.. d][j] layout ----------------
__global__ __launch_bounds__(256) void vtrans_kernel(const u16* __restrict__ Vb,
                                                     u16* __restrict__ vtd) {
  int grp, g, r, off, jb, hl, s;
  decode_blk(blockIdx.x, grp, g, r, off, jb, hl, s);
  const int h = grp * 8 + hl;
  const size_t vbase = (size_t)((grp == 0) ? 0u : (grp == 1) ? 8388608u : 12582912u)
                       + (size_t)(s * 8 + hl) * 131072;
  __shared__ u16 t[64 * 128];
  const int tid = threadIdx.x;
#pragma unroll
  for (int i = 0; i < 4; ++i) {
    int c = tid + i * 256;
    int jj = c >> 4, c16 = c & 15;
    size_t pos = (size_t)s * g + off + (size_t)(jb * 64 + jj) * r;
    uint4 d = *(const uint4*)&Vb[pos * 3072 + h * 128 + c16 * 8];
    *(uint4*)((char*)t + jj * 256 + ((c16 * 16) ^ ((jj >> 3) << 4))) = d;
  }
  __syncthreads();
#pragma unroll
  for (int i = 0; i < 4; ++i) {
    int c = tid + i * 256;
    int dd = c >> 3, jc = c & 7;
    u16x8 vals;
#pragma unroll
    for (int q = 0; q < 8; ++q) {
      int row = jc * 8 + q;
      vals[q] = *(const u16*)((const char*)t + row * 256 + ((dd * 2) ^ (jc << 4)));
    }
    *(u16x8*)&vtd[vbase + (size_t)dd * 1024 + jb * 64 + jc * 8] = vals;
  }
}

// ---------------- dilated flash attention ----------------
__global__ __launch_bounds__(256) void attn_kernel(const u16* __restrict__ Qb,
                                                   const u16* __restrict__ Kb,
                                                   const u16* __restrict__ vtd,
                                                   u16* __restrict__ abuf) {
  int grp, g, r, off, qt, hl, s;
  decode_blk(blockIdx.x, grp, g, r, off, qt, hl, s);
  const int h = grp * 8 + hl;
  const size_t vbase = (size_t)((grp == 0) ? 0u : (grp == 1) ? 8388608u : 12582912u)
                       + (size_t)(s * 8 + hl) * 131072;
  const size_t segoff = (size_t)s * g + off;

  const int tid = threadIdx.x;
  const int lane = tid & 63, w = tid >> 6;
  const int lr = lane & 15, lc = lane >> 4;

  __shared__ u16 Kl[64 * 128];
  __shared__ u16 Vl[128 * 64];
  __shared__ u16 Pl[4][1024];

  const size_t qpos = segoff + (size_t)(qt * 64 + w * 16 + lr) * r;
  const u16* qrow = &Qb[qpos * 3072 + h * 128];
  bf16x8 qf[4];
#pragma unroll
  for (int kc = 0; kc < 4; ++kc) qf[kc] = *(const bf16x8*)&qrow[kc * 32 + lc * 8];

  float m_run[4], l_run[4];
  f32x4 ao[8] = {};
#pragma unroll
  for (int i = 0; i < 4; ++i) { m_run[i] = -1e30f; l_run[i] = 0.f; }

  const float scale = 0.08838834764831845f;

  for (int kt = 0; kt < 16; ++kt) {
    __syncthreads();
#pragma unroll
    for (int i = 0; i < 4; ++i) {
      int c = tid + i * 256;
      int jj = c >> 4, c16 = c & 15;
      size_t kpos = segoff + (size_t)(kt * 64 + jj) * r;
      uint4 kd = *(const uint4*)&Kb[kpos * 3072 + h * 128 + c16 * 8];
      *(uint4*)((char*)Kl + jj * 256 + ((c16 * 16) ^ ((jj & 7) << 4))) = kd;
      int dd = c >> 3, jc = c & 7;
      uint4 vd = *(const uint4*)&vtd[vbase + (size_t)dd * 1024 + kt * 64 + jc * 8];
      *(uint4*)((char*)Vl + dd * 128 + ((jc * 16) ^ ((dd & 7) << 4))) = vd;
    }
    __syncthreads();

    f32x4 sc4[4] = {};
#pragma unroll
    for (int kb = 0; kb < 4; ++kb) {
      const int key = kb * 16 + lr;
      const int swz = (key & 7) << 4;
#pragma unroll
      for (int kc = 0; kc < 4; ++kc) {
        bf16x8 kf = *(const bf16x8*)((const char*)Kl + key * 256 + ((kc * 64 + lc * 16) ^ swz));
        sc4[kb] = __builtin_amdgcn_mfma_f32_16x16x32_bf16(qf[kc], kf, sc4[kb], 0, 0, 0);
      }
    }

    float pv[4][4];
#pragma unroll
    for (int rg = 0; rg < 4; ++rg) {
      float t = fmaxf(fmaxf(sc4[0][rg], sc4[1][rg]), fmaxf(sc4[2][rg], sc4[3][rg]));
#pragma unroll
      for (int sh = 1; sh < 16; sh <<= 1) t = fmaxf(t, __shfl_xor(t, sh, 64));
      t *= scale;
      const float mn = fmaxf(m_run[rg], t);
      const float corr = __expf(m_run[rg] - mn);
      m_run[rg] = mn;
      float sum = 0.f;
#pragma unroll
      for (int kb = 0; kb < 4; ++kb) {
        float p = __expf(sc4[kb][rg] * scale - mn);
        pv[kb][rg] = p; sum += p;
      }
#pragma unroll
      for (int sh = 1; sh < 16; sh <<= 1) sum += __shfl_xor(sum, sh, 64);
      l_run[rg] = l_run[rg] * corr + sum;
#pragma unroll
      for (int nb = 0; nb < 8; ++nb) ao[nb][rg] *= corr;
    }

#pragma unroll
    for (int rg = 0; rg < 4; ++rg) {
      const int q = lc * 4 + rg;
      const int swq = (q & 7) << 4;
#pragma unroll
      for (int kb = 0; kb < 4; ++kb) {
        const int key = kb * 16 + lr;
        *(u16*)((char*)&Pl[w][0] + q * 128 + ((key * 2) ^ swq)) = f2bf(pv[kb][rg]);
      }
    }
    __syncthreads();

#pragma unroll
    for (int kc2 = 0; kc2 < 2; ++kc2) {
      bf16x8 pf = *(const bf16x8*)((const char*)&Pl[w][0] + lr * 128 + ((kc2 * 64 + lc * 16) ^ ((lr & 7) << 4)));
#pragma unroll
      for (int nb = 0; nb < 8; ++nb) {
        const int dd = nb * 16 + lr;
        bf16x8 vf = *(const bf16x8*)((const char*)Vl + dd * 128 + ((kc2 * 64 + lc * 16) ^ ((dd & 7) << 4)));
        ao[nb] = __builtin_amdgcn_mfma_f32_16x16x32_bf16(pf, vf, ao[nb], 0, 0, 0);
      }
    }
  }

#pragma unroll
  for (int rg = 0; rg < 4; ++rg) {
    const float inv = 1.f / l_run[rg];
    const size_t opos = segoff + (size_t)(qt * 64 + w * 16 + lc * 4 + rg) * r;
    u16* orow = &abuf[opos * 3072 + h * 128];
#pragma unroll
    for (int nb = 0; nb < 8; ++nb) orow[nb * 16 + lr] = f2bf(ao[nb][rg] * inv);
  }
}

// ---------------- LayerNorm over 3072 cols; IN_BF/OUT_BF select dtypes ----------------
template<int IN_BF, int OUT_BF>
__global__ __launch_bounds__(256) void ln_kernel(const void* __restrict__ yv,
                                                 const float* __restrict__ gm,
                                                 const float* __restrict__ bt,
                                                 void* __restrict__ outv) {
  const size_t row = blockIdx.x;
  const int tid = threadIdx.x;
  float v[12];
  float s = 0.f, ss = 0.f;
#pragma unroll
  for (int i = 0; i < 3; ++i) {
    if constexpr (IN_BF) {
      u16x4 raw = *(const u16x4*)((const u16*)yv + row * 3072 + tid * 4 + i * 1024);
#pragma unroll
      for (int j = 0; j < 4; ++j) { float f = b2f(raw[j]); v[i * 4 + j] = f; s += f; ss += f * f; }
    } else {
      f32x4 raw = *(const f32x4*)((const float*)yv + row * 3072 + tid * 4 + i * 1024);
#pragma unroll
      for (int j = 0; j < 4; ++j) { float f = raw[j]; v[i * 4 + j] = f; s += f; ss += f * f; }
    }
  }
#pragma unroll
  for (int sh = 1; sh < 64; sh <<= 1) { s += __shfl_xor(s, sh, 64); ss += __shfl_xor(ss, sh, 64); }
  __shared__ float red[8];
  if ((tid & 63) == 0) { red[tid >> 6] = s; red[4 + (tid >> 6)] = ss; }
  __syncthreads();
  s = red[0] + red[1] + red[2] + red[3];
  ss = red[4] + red[5] + red[6] + red[7];
  const float mean = s * (1.f / 3072.f);
  const float var = ss * (1.f / 3072.f) - mean * mean;
  const float rs = rsqrtf(var + 1e-5f);
#pragma unroll
  for (int i = 0; i < 3; ++i) {
    int c = tid * 4 + i * 1024;
    f32x4 g4 = *(const f32x4*)&gm[c];
    f32x4 b4 = *(const f32x4*)&bt[c];
    if constexpr (OUT_BF) {
      u16x4 ob;
#pragma unroll
      for (int j = 0; j < 4; ++j) ob[j] = f2bf((v[i * 4 + j] - mean) * rs * g4[j] + b4[j]);
      *(u16x4*)((u16*)outv + row * 3072 + c) = ob;
    } else {
      f32x4 o;
#pragma unroll
      for (int j = 0; j < 4; ++j) o[j] = (v[i * 4 + j] - mean) * rs * g4[j] + b4[j];
      *(f32x4*)((float*)outv + row * 3072 + c) = o;
    }
  }
}

// ---------------- launch ----------------
extern "C" void kernel_launch(void* const* d_in, const int* in_sizes, int n_in,
                              void* d_out, int out_size, void* d_ws, size_t ws_size,
                              hipStream_t stream) {
  (void)in_sizes; (void)n_in; (void)out_size;
  const float* x    = (const float*)d_in[0];
  const float* ee   = (const float*)d_in[1];
  const float* wqkv = (const float*)d_in[2];
  const float* bqkv = (const float*)d_in[3];
  const float* wout = (const float*)d_in[4];
  const float* bout = (const float*)d_in[5];
  const float* ln1g = (const float*)d_in[6];
  const float* ln1b = (const float*)d_in[7];
  const float* w1   = (const float*)d_in[8];
  const float* b1   = (const float*)d_in[9];
  const float* w2   = (const float*)d_in[10];
  const float* b2   = (const float*)d_in[11];
  const float* ln2g = (const float*)d_in[12];
  const float* ln2b = (const float*)d_in[13];
  float* out = (float*)d_out;

  static const size_t OFF_B1  = 50331648;
  static const size_t OFF_B2  = 100663296;
  static const size_t WS_NEED = 150994944;
  if (ws_size < WS_NEED) return;

  char* ws = (char*)d_ws;
  u16*   xb    = (u16*)(ws);
  u16*   vtd   = (u16*)(ws);
  u16*   wbo   = (u16*)(ws);
  u16*   x1b   = (u16*)(ws);
  u16*   Qb    = (u16*)(ws + OFF_B1);
  u16*   y1b   = (u16*)(ws + OFF_B1);
  u16*   y2b   = (u16*)(ws + OFF_B1);
  u16*   wslot = (u16*)(ws + OFF_B2);
  u16*   abuf  = (u16*)(ws + OFF_B2);
  u16*   Kb    = (u16*)d_out;
  u16*   Vb    = (u16*)((char*)d_out + 50331648);
  u16*   hcd   = (u16*)d_out;

  prep_kernel<<<24576, 256, 0, stream>>>(x, ee, xb);

  // Q,K fused (N=6144, 256^2 tiles, grid 768 = 3 full rounds); V grid 768
  cvt_kernel<<<18432, 256, 0, stream>>>(wqkv, wslot, 18874368);
  gemm8_kernel<7><<<768, 512, 0, stream>>>(xb, wslot, bqkv, Qb, Kb, 6144, 3072);
  cvt_kernel<<<9216, 256, 0, stream>>>(wqkv + 18874368, wslot, 9437184);
  gemmu_kernel<0><<<768, 512, 0, stream>>>(xb, wslot, bqkv + 6144, nullptr, nullptr, nullptr,
                                           Vb, 3072, 3072);

  vtrans_kernel<<<1792, 256, 0, stream>>>(Vb, vtd);
  hipMemsetAsync(abuf, 0, 50331648, stream);
  attn_kernel<<<1792, 256, 0, stream>>>(Qb, Kb, vtd, abuf);

  // y1b = bf16(attn @ w_out^T + b_out + x + ee)
  cvt_kernel<<<9216, 256, 0, stream>>>(wout, wbo, 9437184);
  gemmu_kernel<3><<<768, 512, 0, stream>>>(abuf, wbo, bout, x, nullptr, ee,
                                           y1b, 3072, 3072);
  ln_kernel<1, 1><<<8192, 256, 0, stream>>>(y1b, ln1g, ln1b, x1b);

  // FFN in 2 chunks of 6144: h (bf16) parked in d_out; y2 accumulates bf16 in y2b
  for (int c = 0; c < 2; ++c) {
    cvt_kernel<<<18432, 256, 0, stream>>>(w1 + (size_t)c * 18874368, wslot, 18874368);
    gemm8_kernel<2><<<768, 512, 0, stream>>>(x1b, wslot, b1 + c * 6144, hcd, nullptr, 6144, 3072);
    cvt_strided_kernel<<<18432, 256, 0, stream>>>(w2, wslot, c * 6144);
    if (c == 0)
      gemmu_kernel<8><<<768, 512, 0, stream>>>(hcd, wslot, b2, nullptr, x1b, nullptr,
                                               y2b, 3072, 6144);
    else
      gemmu_kernel<9><<<768, 512, 0, stream>>>(hcd, wslot, b2, nullptr, nullptr, nullptr,
                                               y2b, 3072, 6144);
  }

  ln_kernel<1, 0><<<8192, 256, 0, stream>>>(y2b, ln2g, ln2b, out);
}